// Round 5
// baseline (111.072 us; speedup 1.0000x reference)
//
#include <hip/hip_runtime.h>
#include <math.h>

#define NB    64          // batches
#define NT    262144      // samples per batch
#define CH    64          // samples per chunk (replay granularity, passB)
#define NCK   (NT/CH)     // 4096 chunks per batch
#define NBANDS 6
// passA split: 2 lanes per chunk, 32 chunks per wave, 128 waves per batch

// ws layout (floats)
#define COEF_OFF 0                               // [NB][6][5]
#define MAT_OFF  4096                            // [NB][13][144]: 0..4 = A^(64*2^l), 5..11 = A^(2048*2^m), 12 = A^32
#define T_OFF    (MAT_OFF + NB*1872)             // [NB][128][12] group totals (passA -> scanW)
#define WPRE_OFF (T_OFF + NB*128*12)             // [NB][128][12] state entering each 32-chunk group
                                                 //   rows 0..63 ALSO alias the V64 table between
                                                 //   k_prep and k_passA (scanW overwrites later)
#define D_OFF    (WPRE_OFF + NB*128*12)          // [NB][NCK][12] within-group exclusive states

struct Coef { float b0, b1, b2, a1, a2; };

__device__ __forceinline__ float rfl(float x) {
  return __int_as_float(__builtin_amdgcn_readfirstlane(__float_as_int(x)));
}

__device__ __forceinline__ float cascade_step(float v, float s[12], const Coef cf[NBANDS]) {
#pragma unroll
  for (int k = 0; k < NBANDS; ++k) {
    float s1 = s[2*k], s2 = s[2*k+1];
    float y   = fmaf(cf[k].b0, v, s1);
    float ns1 = fmaf(cf[k].b1, v, fmaf(-cf[k].a1, y, s2));
    float ns2 = fmaf(cf[k].b2, v, -cf[k].a2 * y);
    s[2*k]   = ns1;
    s[2*k+1] = ns2;
    v = y;
  }
  return v;
}

// coefs are wave-uniform: pin them to SGPRs
__device__ __forceinline__ void load_coefs(const float* ws, int batch, Coef cf[NBANDS]) {
  const float* c = ws + COEF_OFF + batch*30;
#pragma unroll
  for (int k = 0; k < NBANDS; ++k) {
    cf[k].b0 = rfl(c[5*k+0]); cf[k].b1 = rfl(c[5*k+1]); cf[k].b2 = rfl(c[5*k+2]);
    cf[k].a1 = rfl(c[5*k+3]); cf[k].a2 = rfl(c[5*k+4]);
  }
}

// ---------------- kernel 1: coefficients + power matrices + V table ----------------
__global__ __launch_bounds__(64) void k_prep(const float* __restrict__ p, const float* __restrict__ W,
                                             const float* __restrict__ bias, const int* __restrict__ srp,
                                             float* __restrict__ ws) {
  __shared__ float prmS[18];
  __shared__ float cfS[30];
  __shared__ float M0[144], M1[144];
  int b = blockIdx.x, tid = threadIdx.x;
  const float lo[18] = {-24.f,20.f,0.1f,  -24.f,200.f,0.1f,  -24.f,200.f,0.1f,
                        -24.f,2000.f,0.1f, -24.f,4000.f,0.1f, -24.f,4000.f,0.1f};
  const float hi[18] = { 24.f,200.f,10.f,  24.f,2000.f,10.f,  24.f,2000.f,10.f,
                         24.f,8000.f,10.f, 24.f,12000.f,10.f, 24.f,12000.f,10.f};
  if (tid < 18) {
    float acc = bias[tid];
    for (int j = 0; j < 22; ++j) acc = fmaf(W[tid*22+j], p[b*22+j], acc);
    float sg = 1.f / (1.f + expf(-acc));
    prmS[tid] = sg * (hi[tid] - lo[tid]) + lo[tid];
  }
  __syncthreads();
  if (tid < 6) {
    int k = tid;
    float g = prmS[3*k], f = prmS[3*k+1], q = prmS[3*k+2];
    float sr = (float)srp[0];
    float A  = powf(10.f, g * (1.f/40.f));
    float w0 = 6.28318530717958647692f * (f / sr);
    float al = sinf(w0) / (2.f*q);
    float c  = cosf(w0);
    float sA = sqrtf(A);
    float b0,b1,b2,a0,a1,a2;
    if (k == 0) {            // low shelf
      b0 = A*((A+1.f) - (A-1.f)*c + 2.f*sA*al);
      b1 = 2.f*A*((A-1.f) - (A+1.f)*c);
      b2 = A*((A+1.f) - (A-1.f)*c - 2.f*sA*al);
      a0 = (A+1.f) + (A-1.f)*c + 2.f*sA*al;
      a1 = -2.f*((A-1.f) + (A+1.f)*c);
      a2 = (A+1.f) + (A-1.f)*c - 2.f*sA*al;
    } else if (k == 5) {     // high shelf
      b0 = A*((A+1.f) + (A-1.f)*c + 2.f*sA*al);
      b1 = -2.f*A*((A-1.f) + (A+1.f)*c);
      b2 = A*((A+1.f) + (A-1.f)*c - 2.f*sA*al);
      a0 = (A+1.f) - (A-1.f)*c + 2.f*sA*al;
      a1 = 2.f*((A-1.f) - (A+1.f)*c);
      a2 = (A+1.f) - (A-1.f)*c - 2.f*sA*al;
    } else {                 // peaking
      b0 = 1.f + al*A;
      b1 = -2.f*c;
      b2 = 1.f - al*A;
      a0 = 1.f + al/A;
      a1 = -2.f*c;
      a2 = 1.f - al/A;
    }
    float inv = 1.f/a0;
    float* cws = ws + COEF_OFF + b*30;
    cws[5*k+0] = cfS[5*k+0] = b0*inv;
    cws[5*k+1] = cfS[5*k+1] = b1*inv;
    cws[5*k+2] = cfS[5*k+2] = b2*inv;
    cws[5*k+3] = cfS[5*k+3] = a1*inv;
    cws[5*k+4] = cfS[5*k+4] = a2*inv;
  }
  __syncthreads();

  Coef cf[NBANDS];
#pragma unroll
  for (int k = 0; k < NBANDS; ++k) {
    cf[k].b0 = cfS[5*k+0]; cf[k].b1 = cfS[5*k+1]; cf[k].b2 = cfS[5*k+2];
    cf[k].a1 = cfS[5*k+3]; cf[k].a2 = cfS[5*k+4];
  }
  if (tid < 12) {
    float s[12];
#pragma unroll
    for (int r = 0; r < 12; ++r) s[r] = (r == tid) ? 1.f : 0.f;
    cascade_step(0.f, s, cf);
#pragma unroll
    for (int r = 0; r < 12; ++r) M0[r*12 + tid] = s[r];   // M0 = A (state transition)
  }
  __syncthreads();

  // per-thread V accumulator: w = A^(63-tid) * B (V64 table).
  float w[12];
#pragma unroll
  for (int r = 0; r < 12; ++r) w[r] = 0.f;
  cascade_step(1.f, w, cf);          // w = B
  int e63 = 63 - tid;

  float* S = M0; float* D = M1;
  float* mout = ws + MAT_OFF + (size_t)b*1872;
  for (int q = 0; q < 6; ++q) {       // S == A^(2^q) at loop entry; -> A^64 after
    if ((e63 >> q) & 1) {
      float t[12];
#pragma unroll
      for (int r = 0; r < 12; ++r) {
        float acc = 0.f;
#pragma unroll
        for (int k = 0; k < 12; ++k) acc = fmaf(S[r*12+k], w[k], acc);
        t[r] = acc;
      }
#pragma unroll
      for (int r = 0; r < 12; ++r) w[r] = t[r];
    }
    if (q == 5) {                     // S == A^32: store to slot 12
      for (int e = tid; e < 144; e += 64) mout[12*144 + e] = S[e];
    }
    for (int e = tid; e < 144; e += 64) {
      int r = e/12, c = e%12;
      float acc = 0.f;
#pragma unroll
      for (int k = 0; k < 12; ++k) acc = fmaf(S[r*12+k], S[k*12+c], acc);
      D[e] = acc;
    }
    __syncthreads();
    float* t = S; S = D; D = t;
  }
  // store V64 (rows 0..63 of WPRE region; consumed by passA, overwritten by scanW)
  {
    float* vout = ws + WPRE_OFF + (size_t)b*1536;
#pragma unroll
    for (int r = 0; r < 12; ++r) vout[tid*12 + r] = w[r];
  }
  // slots 0..11: A^64, A^128, ..., A^131072 (each squaring doubles)
  for (int e = tid; e < 144; e += 64) mout[e] = S[e];
  for (int l = 1; l < 12; ++l) {
    for (int e = tid; e < 144; e += 64) {
      int r = e/12, c = e%12;
      float acc = 0.f;
#pragma unroll
      for (int k = 0; k < 12; ++k) acc = fmaf(S[r*12+k], S[k*12+c], acc);
      D[e] = acc;
    }
    __syncthreads();
    float* t = S; S = D; D = t;
    for (int e = tid; e < 144; e += 64) mout[l*144 + e] = S[e];
  }
}

// ---------------- passA: split-lane V-dot (2 lanes/chunk) + 32-wide KS ----------------
// Lane l (l<32) and lane l+32 each V-dot one HALF of chunk (wv*32+l) with the same
// wave-uniform table rows V64[32..63] = A^(31-t)B; combine fin = A^32*p_lo + p_hi.
// 8192 waves total -> 2048 blocks -> 8 blocks/CU: tests the latency/parallelism theory.
__global__ __launch_bounds__(256, 8) void k_passA(const float* __restrict__ x, float* __restrict__ ws) {
  __shared__ float KM[6][144];        // 0..4 = A^(64*2^l), 5 = A^32
  int tid = threadIdx.x, wib = tid >> 6, lane = tid & 63;
  int gw = blockIdx.x*4 + wib;        // 0..8191
  int batch = gw >> 7, wv = gw & 127;
  int batch_b = blockIdx.x >> 5;      // 32 blocks per batch (block-uniform)

  const float* mb = ws + MAT_OFF + (size_t)batch_b*1872;
  for (int e = tid; e < 864; e += 256) {
    float v = (e < 720) ? mb[e] : mb[12*144 + (e - 720)];
    KM[e/144][e%144] = v;
  }
  __syncthreads();

  int c = lane & 31, h = lane >> 5;
  const float4* x4 = (const float4*)x;
  size_t gbase4 = (size_t)batch*65536 + (size_t)(wv*32 + c)*16 + (size_t)h*8;
  const float* Vb = ws + WPRE_OFF + (size_t)batch_b*1536 + 32*12;  // V64 rows 32..63 (wave-uniform)

  float4 xv[8];
#pragma unroll
  for (int k = 0; k < 8; ++k) xv[k] = x4[gbase4 + k];

  // half-chunk V-dot: p = sum_t A^(31-t)B * x[half_t]
  float p[12];
#pragma unroll
  for (int r = 0; r < 12; ++r) p[r] = 0.f;
#pragma unroll
  for (int k = 0; k < 8; ++k) {
    const float* vr = Vb + k*48;
#pragma unroll
    for (int r = 0; r < 12; ++r) {
      float acc = p[r];
      acc = fmaf(vr[r],      xv[k].x, acc);
      acc = fmaf(vr[12 + r], xv[k].y, acc);
      acc = fmaf(vr[24 + r], xv[k].z, acc);
      acc = fmaf(vr[36 + r], xv[k].w, acc);
      p[r] = acc;
    }
  }

  // combine halves on lanes<32: s = A^32 * p_lo + p_hi
  float s[12];
#pragma unroll
  for (int r = 0; r < 12; ++r) s[r] = __shfl_down(p[r], 32);
#pragma unroll
  for (int r = 0; r < 12; ++r) {
    float acc = s[r];
#pragma unroll
    for (int k = 0; k < 12; ++k) acc = fmaf(KM[5][r*12+k], p[k], acc);
    s[r] = acc;
  }

  // KS over 32 chunk-finals (lanes 0..31 meaningful), KM[l] = A^(64*2^l)
#pragma unroll
  for (int l = 0; l < 5; ++l) {
    const int pd = 1 << l;
    float nb[12];
#pragma unroll
    for (int r = 0; r < 12; ++r) nb[r] = __shfl_up(s[r], pd);
    if (lane >= pd) {
#pragma unroll
      for (int r = 0; r < 12; ++r) {
        float acc = s[r];
#pragma unroll
        for (int cc = 0; cc < 12; ++cc) acc = fmaf(KM[l][r*12+cc], nb[cc], acc);
        s[r] = acc;
      }
    }
  }

  if (lane == 31) {                   // group total (32 chunks = 2048 samples)
    float4* tp = (float4*)(ws + T_OFF + ((size_t)batch*128 + wv)*12);
    tp[0] = make_float4(s[0], s[1], s[2],  s[3]);
    tp[1] = make_float4(s[4], s[5], s[6],  s[7]);
    tp[2] = make_float4(s[8], s[9], s[10], s[11]);
  }

  float e[12];
#pragma unroll
  for (int r = 0; r < 12; ++r) e[r] = __shfl_up(s[r], 1);
  if (lane == 0) {
#pragma unroll
    for (int r = 0; r < 12; ++r) e[r] = 0.f;
  }
  if (lane < 32) {
    int chunk = wv*32 + lane;
    float4* dp = (float4*)(ws + D_OFF + ((size_t)batch*NCK + chunk)*12);
    dp[0] = make_float4(e[0], e[1], e[2],  e[3]);
    dp[1] = make_float4(e[4], e[5], e[6],  e[7]);
    dp[2] = make_float4(e[8], e[9], e[10], e[11]);
  }
}

// ---------------- scan over 128 group totals (2 waves + LDS bridge) ----------------
__global__ __launch_bounds__(128) void k_scanW(float* __restrict__ ws) {
  __shared__ float WM[7][144];        // WM[m] = A^(2048*2^m), m=0..6 (slots 5..11)
  __shared__ float bridge[12];
  int b = blockIdx.x, t = threadIdx.x, lane = t & 63, w = t >> 6;
  const float* mb = ws + MAT_OFF + (size_t)b*1872 + 5*144;
  for (int e = t; e < 1008; e += 128) WM[e/144][e%144] = mb[e];
  __syncthreads();

  const float4* tp = (const float4*)(ws + T_OFF + ((size_t)b*128 + t)*12);
  float4 a0 = tp[0], a1 = tp[1], a2 = tp[2];
  float s[12] = {a0.x,a0.y,a0.z,a0.w, a1.x,a1.y,a1.z,a1.w, a2.x,a2.y,a2.z,a2.w};

  // in-wave KS over 64 slots (slot transform = A^2048)
#pragma unroll
  for (int m = 0; m < 6; ++m) {
    const int pd = 1 << m;
    float nb[12];
#pragma unroll
    for (int r = 0; r < 12; ++r) nb[r] = __shfl_up(s[r], pd);
    if (lane >= pd) {
#pragma unroll
      for (int r = 0; r < 12; ++r) {
        float acc = s[r];
#pragma unroll
        for (int c = 0; c < 12; ++c) acc = fmaf(WM[m][r*12+c], nb[c], acc);
        s[r] = acc;
      }
    }
  }
  if (t == 63) {
#pragma unroll
    for (int r = 0; r < 12; ++r) bridge[r] = s[r];
  }
  __syncthreads();

  // wave 1: add A^(2048*(lane+1)) * bridge
  if (w == 1) {
    int k = lane + 1;                 // 1..64
    float R[12];
#pragma unroll
    for (int r = 0; r < 12; ++r) R[r] = bridge[r];
#pragma unroll
    for (int bit = 0; bit < 7; ++bit) {
      if ((k >> bit) & 1) {
        float tv[12];
#pragma unroll
        for (int r = 0; r < 12; ++r) {
          float acc = 0.f;
#pragma unroll
          for (int c = 0; c < 12; ++c) acc = fmaf(WM[bit][r*12+c], R[c], acc);
          tv[r] = acc;
        }
#pragma unroll
        for (int r = 0; r < 12; ++r) R[r] = tv[r];
      }
    }
#pragma unroll
    for (int r = 0; r < 12; ++r) s[r] += R[r];
  }

  // exclusive prefix
  float e[12];
#pragma unroll
  for (int r = 0; r < 12; ++r) e[r] = __shfl_up(s[r], 1);
  if (t == 0) {
#pragma unroll
    for (int r = 0; r < 12; ++r) e[r] = 0.f;
  }
  if (t == 64) {
#pragma unroll
    for (int r = 0; r < 12; ++r) e[r] = bridge[r];
  }
  float4* wp = (float4*)(ws + WPRE_OFF + ((size_t)b*128 + t)*12);
  wp[0] = make_float4(e[0], e[1], e[2],  e[3]);
  wp[1] = make_float4(e[4], e[5], e[6],  e[7]);
  wp[2] = make_float4(e[8], e[9], e[10], e[11]);
}

// ---------------- passB: reconstruct incoming state + replay + write y ----------------
__global__ __launch_bounds__(256) void k_passB(const float* __restrict__ x, const float* __restrict__ ws,
                                               float* __restrict__ out) {
  __shared__ float4 buf[4][2][256];
  __shared__ float KM[5][144];        // A^(64*2^l), l=0..4
  int tid = threadIdx.x, wib = tid >> 6, lane = tid & 63;
  int gw = blockIdx.x*4 + wib;
  int batch = gw >> 6, wv = gw & 63;
  int batch_b = blockIdx.x >> 4;

  const float* mb = ws + MAT_OFF + (size_t)batch_b*1872;
  for (int e = tid; e < 720; e += 256) KM[e/144][e%144] = mb[e];
  __syncthreads();

  const float4* x4 = (const float4*)x;
  float4* out4 = (float4*)out;
  size_t gbase4 = (size_t)batch*65536 + (size_t)wv*1024;
  int r2 = lane >> 2, c2 = lane & 3;
  float4* bufA = buf[wib][0];
  float4* bufB = buf[wib][1];

  float4 va[4], vb[4];
#pragma unroll
  for (int j = 0; j < 4; ++j) va[j] = x4[gbase4 + (size_t)(j*16 + r2)*16 + c2];

  Coef cf[NBANDS];
  load_coefs(ws, batch, cf);

  // incoming state: D (within-group exclusive) + A^(64*j) * Wpre[group]
  int chunk = wv*64 + lane;
  int g = wv*2 + (lane >> 5), j = lane & 31;
  const float4* dp = (const float4*)(ws + D_OFF + ((size_t)batch*NCK + chunk)*12);
  float4 e0 = dp[0], e1 = dp[1], e2 = dp[2];
  const float4* wp = (const float4*)(ws + WPRE_OFF + ((size_t)batch*128 + g)*12);
  float4 w0 = wp[0], w1 = wp[1], w2 = wp[2];
  float R[12] = {w0.x,w0.y,w0.z,w0.w, w1.x,w1.y,w1.z,w1.w, w2.x,w2.y,w2.z,w2.w};
#pragma unroll
  for (int l = 0; l < 5; ++l) {
    float t[12];
#pragma unroll
    for (int r = 0; r < 12; ++r) {
      float acc = 0.f;
#pragma unroll
      for (int c = 0; c < 12; ++c) acc = fmaf(KM[l][r*12+c], R[c], acc);
      t[r] = acc;
    }
    bool sel = (j >> l) & 1;
#pragma unroll
    for (int r = 0; r < 12; ++r) R[r] = sel ? t[r] : R[r];
  }
  float s[12] = {e0.x+R[0], e0.y+R[1], e0.z+R[2],  e0.w+R[3],
                 e1.x+R[4], e1.y+R[5], e1.z+R[6],  e1.w+R[7],
                 e2.x+R[8], e2.y+R[9], e2.z+R[10], e2.w+R[11]};

#pragma unroll
  for (int j2 = 0; j2 < 4; ++j2) bufA[c2*64 + j2*16 + r2] = va[j2];
  asm volatile("s_waitcnt lgkmcnt(0)" ::: "memory");

#pragma unroll
  for (int q = 0; q < 4; ++q) {
    float4* bp = (q & 1) ? bufB : bufA;
    float4* bn = (q & 1) ? bufA : bufB;
    float4* vr = (q & 1) ? va : vb;
    if (q < 3) {
#pragma unroll
      for (int j2 = 0; j2 < 4; ++j2)
        vr[j2] = x4[gbase4 + (size_t)(j2*16 + r2)*16 + (q+1)*4 + c2];
    }
#pragma unroll
    for (int t = 0; t < 4; ++t) {
      float4 xv = bp[t*64 + lane];
      float4 yv;
      yv.x = cascade_step(xv.x, s, cf);
      yv.y = cascade_step(xv.y, s, cf);
      yv.z = cascade_step(xv.z, s, cf);
      yv.w = cascade_step(xv.w, s, cf);
      bp[t*64 + lane] = yv;
    }
    asm volatile("s_waitcnt lgkmcnt(0)" ::: "memory");
    // transpose coop-store of quarter q (16 full 64B lines per instr)
#pragma unroll
    for (int j2 = 0; j2 < 4; ++j2) {
      float4 w = bp[c2*64 + j2*16 + r2];
      out4[gbase4 + (size_t)(j2*16 + r2)*16 + q*4 + c2] = w;
    }
    if (q < 3) {
#pragma unroll
      for (int j2 = 0; j2 < 4; ++j2) bn[c2*64 + j2*16 + r2] = vr[j2];
      asm volatile("s_waitcnt lgkmcnt(0)" ::: "memory");
    }
  }
}

extern "C" void kernel_launch(void* const* d_in, const int* in_sizes, int n_in,
                              void* d_out, int out_size, void* d_ws, size_t ws_size,
                              hipStream_t stream) {
  const float* x    = (const float*)d_in[0];
  const float* p    = (const float*)d_in[1];
  const float* W    = (const float*)d_in[2];
  const float* bias = (const float*)d_in[3];
  const int*   sr   = (const int*)d_in[4];
  float* ws  = (float*)d_ws;
  float* out = (float*)d_out;

  hipLaunchKernelGGL(k_prep,  dim3(NB),   dim3(64),  0, stream, p, W, bias, sr, ws);
  hipLaunchKernelGGL(k_passA, dim3(2048), dim3(256), 0, stream, x, ws);
  hipLaunchKernelGGL(k_scanW, dim3(NB),   dim3(128), 0, stream, ws);
  hipLaunchKernelGGL(k_passB, dim3(1024), dim3(256), 0, stream, x, ws, out);
}